// Round 11
// baseline (413.251 us; speedup 1.0000x reference)
//
#include <hip/hip_runtime.h>
#include <math.h>

#define TT 512
#define GG 3
#define HH 32
#define DD 128

typedef __fp16 fp16x2 __attribute__((ext_vector_type(2)));

__device__ __forceinline__ uint32_t pack2(float a, float b) {
  auto p = __builtin_amdgcn_cvt_pkrtz(a, b);   // __fp16 ext_vector(2)
  return __builtin_bit_cast(uint32_t, p);
}
__device__ __forceinline__ float fdot2u(uint32_t a, uint32_t b, float c) {
  return __builtin_amdgcn_fdot2(__builtin_bit_cast(fp16x2, a),
                                __builtin_bit_cast(fp16x2, b), c, false);
}
__device__ __forceinline__ float fast_tanh(float x) {
  float e = __expf(2.0f * x);
  return 1.0f - 2.0f * __builtin_amdgcn_rcpf(1.0f + e);
}

// 64 lanes per sequence -> 6144 waves = 6 waves/SIMD (2x the TLP of the
// 32-lane framing; all previous structures plateaued ~stall-bound at <=3
// waves/SIMD). Lane l (jj=l&31, half=l>>5): computes r[jj] (half 0) or z[jj]
// (half 1) -- one uniform instruction stream with per-lane constants -- plus
// half of n's 32-wide dot (k in [16*half,16*half+16)). Two __shfl_xor(.,32)
// combine n partials and swap r<->z so every lane finishes h[jj] identically;
// both halves store the same f16 to LDS (same-value write, deterministic).
// Matvec via v_dot2_f32_f16 (f16 weights with log2e scales pre-folded, f32
// acc). h exchange wave-synchronous (no __syncthreads in loop).
__global__ __launch_bounds__(256, 5) void gru_scan_w64(
    const float* __restrict__ x, const float* __restrict__ W_ih,
    const float* __restrict__ W_hh, const float* __restrict__ b_ih,
    const float* __restrict__ b_hh, float* __restrict__ hout, int B) {
  const int tid = threadIdx.x;
  const int wv = tid >> 6;        // wave in block = sequence
  const int lane = tid & 63;
  const int jj = lane & 31;       // h index owned by this lane
  const int half = lane >> 5;     // 0: r-gate, 1: z-gate (+ n k-half)
  const int p = blockIdx.x * 4 + wv;   // global sequence = b*G + g
  const int g = p % GG;
  const float L2E = 1.44269504088896340736f;

  __shared__ float xs[4][TT + 1];      // per-seq x (broadcast reads)
  __shared__ uint32_t hb[2][4][20];    // f16-pair h, double buffered

  // ---- cooperative x preload (one-time) ----
#pragma unroll 4
  for (int i = tid; i < 4 * TT; i += 256) {
    int si = i >> 9, t = i & (TT - 1);
    int pp = blockIdx.x * 4 + si;
    xs[si][t] = x[((size_t)(pp / GG) * TT + t) * GG + (pp % GG)];
  }

  // ---- weights as f16 pairs, log2e-scaled: r,z by -L2E; n by +2L2E ----
  const float* Wg = W_hh + (size_t)g * 3 * HH * HH;
  const float* rowA = Wg + (size_t)(half * HH + jj) * HH;        // r or z row
  uint32_t wA[16];
#pragma unroll
  for (int m = 0; m < 16; ++m)
    wA[m] = pack2(rowA[2 * m] * (-L2E), rowA[2 * m + 1] * (-L2E));
  const float* rowN = Wg + (size_t)(2 * HH + jj) * HH + half * 16;  // n half-row
  uint32_t wN[8];
#pragma unroll
  for (int m = 0; m < 8; ++m)
    wN[m] = pack2(rowN[2 * m] * (2.0f * L2E), rowN[2 * m + 1] * (2.0f * L2E));

  const int ia = g * 96 + half * 32 + jj;   // r (half0) / z (half1) index
  const float wiA = W_ih[ia] * (-L2E);
  const float bA = (b_ih[ia] + b_hh[ia]) * (-L2E);
  const float wiN2 = W_ih[g * 96 + 64 + jj] * (2.0f * L2E);
  const float bN2 = b_ih[g * 96 + 64 + jj] * (2.0f * L2E);
  const float bHN2 = (half == 0) ? b_hh[g * 96 + 64 + jj] * (2.0f * L2E) : 0.0f;

  if (lane < 16) hb[0][wv][lane] = 0u;   // zero h buffer 0 (own wave's slot)
  __syncthreads();                        // covers xs staging (prologue only)

  float h = 0.0f;

#define STEP(SRC, DST, TC)                                                     \
  {                                                                            \
    float xv = xs[wv][TC];                                                     \
    uint4 h0 = *(const uint4*)&hb[SRC][wv][0];                                 \
    uint4 h1 = *(const uint4*)&hb[SRC][wv][4];                                 \
    uint4 h2 = *(const uint4*)&hb[SRC][wv][8];                                 \
    uint4 h3 = *(const uint4*)&hb[SRC][wv][12];                                \
    uint4 n01 = *(const uint4*)&hb[SRC][wv][half * 8];                         \
    uint4 n23 = *(const uint4*)&hb[SRC][wv][half * 8 + 4];                     \
    float a0 = fmaf(xv, wiA, bA), a1 = 0.0f;                                   \
    a0 = fdot2u(wA[0], h0.x, a0);  a1 = fdot2u(wA[8], h2.x, a1);               \
    a0 = fdot2u(wA[1], h0.y, a0);  a1 = fdot2u(wA[9], h2.y, a1);               \
    a0 = fdot2u(wA[2], h0.z, a0);  a1 = fdot2u(wA[10], h2.z, a1);              \
    a0 = fdot2u(wA[3], h0.w, a0);  a1 = fdot2u(wA[11], h2.w, a1);              \
    a0 = fdot2u(wA[4], h1.x, a0);  a1 = fdot2u(wA[12], h3.x, a1);              \
    a0 = fdot2u(wA[5], h1.y, a0);  a1 = fdot2u(wA[13], h3.y, a1);              \
    a0 = fdot2u(wA[6], h1.z, a0);  a1 = fdot2u(wA[14], h3.z, a1);              \
    a0 = fdot2u(wA[7], h1.w, a0);  a1 = fdot2u(wA[15], h3.w, a1);              \
    float n0 = bHN2, n1 = 0.0f;                                                \
    n0 = fdot2u(wN[0], n01.x, n0); n1 = fdot2u(wN[4], n23.x, n1);              \
    n0 = fdot2u(wN[1], n01.y, n0); n1 = fdot2u(wN[5], n23.y, n1);              \
    n0 = fdot2u(wN[2], n01.z, n0); n1 = fdot2u(wN[6], n23.z, n1);              \
    n0 = fdot2u(wN[3], n01.w, n0); n1 = fdot2u(wN[7], n23.w, n1);              \
    float sigA = __builtin_amdgcn_rcpf(1.0f + __builtin_amdgcn_exp2f(a0 + a1)); \
    float accN = n0 + n1;                                                      \
    float otherA = __shfl_xor(sigA, 32);                                       \
    float otherN = __shfl_xor(accN, 32);                                       \
    float rr = half ? otherA : sigA;                                           \
    float zz = half ? sigA : otherA;                                           \
    float ghn = accN + otherN;                                                 \
    float pn = fmaf(rr, ghn, fmaf(xv, wiN2, bN2));                             \
    float u = __builtin_amdgcn_rcpf(1.0f + __builtin_amdgcn_exp2f(pn));        \
    float nn = fmaf(-2.0f, u, 1.0f);                                           \
    h = fmaf(zz, h - nn, nn);                                                  \
    ((__fp16*)&hb[DST][wv][0])[jj] = (__fp16)h;                                \
    __builtin_amdgcn_wave_barrier();                                           \
  }

#pragma unroll 1
  for (int t = 0; t < TT; t += 2) {
    STEP(0, 1, t)
    STEP(1, 0, t + 1)
  }
#undef STEP

  if (lane < 32) hout[(size_t)p * HH + jj] = h;
}

// One block per b: query -> scores -> softmax -> weighted rep -> out row,
// then broadcast-write the row across all T positions (coalesced float4).
__global__ __launch_bounds__(256) void epilogue(
    const float* __restrict__ ctx, const float* __restrict__ hf,
    const float* __restrict__ Wq, const float* __restrict__ bq,
    const float* __restrict__ Ws, const float* __restrict__ bs,
    const float* __restrict__ Wo, const float* __restrict__ bo,
    const float* __restrict__ logT, float* __restrict__ out, int B) {
  const int b = blockIdx.x;
  const int tid = threadIdx.x;
  __shared__ float sc[DD];
  __shared__ float sw[HH];
  __shared__ float srow[DD];
  if (tid < DD) sc[tid] = ctx[(size_t)b * DD + tid];
  __syncthreads();
  if (tid < HH) {
    float q = bq[tid];
#pragma unroll 4
    for (int d = 0; d < DD; ++d) q = fmaf(sc[d], Wq[d * HH + tid], q);
    float h0 = hf[((size_t)b * 3 + 0) * HH + tid];
    float h1 = hf[((size_t)b * 3 + 1) * HH + tid];
    float h2 = hf[((size_t)b * 3 + 2) * HH + tid];
    float wsv = Ws[tid];
    float s0 = fast_tanh(h0 + q) * wsv;
    float s1 = fast_tanh(h1 + q) * wsv;
    float s2 = fast_tanh(h2 + q) * wsv;
#pragma unroll
    for (int off = 16; off >= 1; off >>= 1) {
      s0 += __shfl_xor(s0, off, 32);
      s1 += __shfl_xor(s1, off, 32);
      s2 += __shfl_xor(s2, off, 32);
    }
    float bsv = bs[0];
    float tmp = fmaxf(__expf(logT[0]), 0.1f);
    float inv = 1.0f / tmp;
    s0 = (s0 + bsv) * inv; s1 = (s1 + bsv) * inv; s2 = (s2 + bsv) * inv;
    float m = fmaxf(s0, fmaxf(s1, s2));
    float e0 = __expf(s0 - m), e1 = __expf(s1 - m), e2 = __expf(s2 - m);
    float den = 1.0f / (e0 + e1 + e2);
    float a0 = e0 * den, a1 = e1 * den, a2 = e2 * den;
    sw[tid] = a0 * h0 + a1 * h1 + a2 * h2;
    if (tid == 0) {
      size_t aoff = (size_t)B * TT * DD + (size_t)b * 3;
      out[aoff] = a0; out[aoff + 1] = a1; out[aoff + 2] = a2;
    }
  }
  __syncthreads();
  if (tid < DD) {
    float o = bo[tid];
#pragma unroll
    for (int h = 0; h < HH; ++h) o = fmaf(sw[h], Wo[h * DD + tid], o);
    srow[tid] = o;
  }
  __syncthreads();
  const float4 v = *(const float4*)&srow[(tid & 31) * 4];
  float4* o4 = (float4*)out + (size_t)b * (TT * DD / 4);
#pragma unroll 4
  for (int i = tid; i < TT * DD / 4; i += 256) {
    o4[i] = v;
  }
}

extern "C" void kernel_launch(void* const* d_in, const int* in_sizes, int n_in,
                              void* d_out, int out_size, void* d_ws, size_t ws_size,
                              hipStream_t stream) {
  const float* x    = (const float*)d_in[0];
  const float* ctx  = (const float*)d_in[1];
  const float* W_ih = (const float*)d_in[2];
  const float* W_hh = (const float*)d_in[3];
  const float* b_ih = (const float*)d_in[4];
  const float* b_hh = (const float*)d_in[5];
  const float* Wq   = (const float*)d_in[6];
  const float* bq   = (const float*)d_in[7];
  const float* Ws   = (const float*)d_in[8];
  const float* bs   = (const float*)d_in[9];
  const float* Wo   = (const float*)d_in[10];
  const float* bo   = (const float*)d_in[11];
  const float* logT = (const float*)d_in[12];
  float* out = (float*)d_out;
  const int B = in_sizes[0] / (TT * GG);

  float* hf = (float*)d_ws;  // B*G*H floats

  dim3 g1((B * GG) / 4);
  gru_scan_w64<<<g1, 256, 0, stream>>>(x, W_ih, W_hh, b_ih, b_hh, hf, B);
  epilogue<<<B, 256, 0, stream>>>(ctx, hf, Wq, bq, Ws, bs, Wo, bo, logT, out, B);
}

// Round 12
// 293.417 us; speedup vs baseline: 1.4084x; 1.4084x over previous
//
#include <hip/hip_runtime.h>
#include <math.h>

#define TT 512
#define GG 3
#define HH 32
#define DD 128

typedef _Float16 half8 __attribute__((ext_vector_type(8)));
typedef float f32x4 __attribute__((ext_vector_type(4)));

__device__ __forceinline__ uint32_t pack2(float a, float b) {
  auto p = __builtin_amdgcn_cvt_pkrtz(a, b);
  return __builtin_bit_cast(uint32_t, p);
}
__device__ __forceinline__ float fast_tanh(float x) {
  float e = __expf(2.0f * x);
  return 1.0f - 2.0f * __builtin_amdgcn_rcpf(1.0f + e);
}

// 16-seq group per 256-thread block, FOUR waves: wave (T=wv>>1, P=wv&1) owns
// j-tile T (MFMA, redundant within the T-pair) and reg-pair P of the C tile.
// Per wave per step: 1 b128 broadcast h-read, 3 MFMA, only 2 j x 3 gates =
// 12 transcendentals (the per-wave trans chain was the round-3/5 bottleneck:
// 48 resp. 24 trans at ~16cy each), 1 packed ds_write_b32, 1 barrier.
__global__ __launch_bounds__(256) void gru_scan_mfma4(
    const float* __restrict__ x, const float* __restrict__ W_ih,
    const float* __restrict__ W_hh, const float* __restrict__ b_ih,
    const float* __restrict__ b_hh, float* __restrict__ hout, int B) {
  const int tid = threadIdx.x;
  const int wv = tid >> 6;
  const int lane = tid & 63;
  const int col = lane & 15;   // seq for B/C; m-row for A
  const int grp = lane >> 4;   // k-block for A/B; row-group for C
  const int T = wv >> 1;       // j-tile
  const int P = wv & 1;        // reg-pair within C (regs 2P, 2P+1)
  const int nb = B / 16;
  const int g = blockIdx.x / nb;
  const int b0 = (blockIdx.x % nb) * 16;
  const float L2E = 1.44269504088896340736f;

  __shared__ float xlds[16][TT + 1];
  __shared__ uint32_t hbuf[2][16][20];

  // ---- x preload (one-time) ----
#pragma unroll 4
  for (int i = tid; i < 16 * TT; i += 256) {
    int s = i >> 9, t = i & (TT - 1);
    xlds[s][t] = x[((size_t)(b0 + s) * TT + t) * GG + g];
  }

  // ---- A fragments for j-tile T (pre-scaled for exp2) ----
  half8 Af[3];
  const float* Wg = W_hh + (size_t)g * 3 * HH * HH;
#pragma unroll
  for (int gam = 0; gam < 3; ++gam) {
    const float sc = (gam == 2) ? 2.0f * L2E : -L2E;
    const float* src = Wg + (size_t)(gam * 32 + T * 16 + col) * HH + grp * 8;
    half8 a;
#pragma unroll
    for (int i = 0; i < 8; ++i) a[i] = (_Float16)(src[i] * sc);
    Af[gam] = a;
  }

  // ---- gate constants for this wave's 2 j's: j = T*16+grp*4+2P (+1) ----
  float wiR[2], wiZ[2], wiN[2], bR[2], bZ[2], bN[2], bHN[2];
#pragma unroll
  for (int k = 0; k < 2; ++k) {
    int j = T * 16 + grp * 4 + 2 * P + k;
    wiR[k] = W_ih[g * 96 + j] * (-L2E);
    wiZ[k] = W_ih[g * 96 + 32 + j] * (-L2E);
    wiN[k] = W_ih[g * 96 + 64 + j] * (2.0f * L2E);
    bR[k] = (b_ih[g * 96 + j] + b_hh[g * 96 + j]) * (-L2E);
    bZ[k] = (b_ih[g * 96 + 32 + j] + b_hh[g * 96 + 32 + j]) * (-L2E);
    bN[k] = b_ih[g * 96 + 64 + j] * (2.0f * L2E);
    bHN[k] = b_hh[g * 96 + 64 + j] * (2.0f * L2E);
  }

  float ho[2] = {0.0f, 0.0f};
  for (int i = tid; i < 320; i += 256) ((uint32_t*)hbuf)[i] = 0u;  // buf 0
  __syncthreads();

  const f32x4 zero = {0.f, 0.f, 0.f, 0.f};

#define GRU_STEP(SRC, DST, TC)                                                 \
  {                                                                            \
    float xv = xlds[col][TC];                                                  \
    half8 Bf = *(const half8*)&hbuf[SRC][col][grp * 4];                        \
    f32x4 Cr = __builtin_amdgcn_mfma_f32_16x16x32_f16(Af[0], Bf, zero, 0, 0, 0); \
    f32x4 Cz = __builtin_amdgcn_mfma_f32_16x16x32_f16(Af[1], Bf, zero, 0, 0, 0); \
    f32x4 Cn = __builtin_amdgcn_mfma_f32_16x16x32_f16(Af[2], Bf, zero, 0, 0, 0); \
    float cr0 = P ? Cr[2] : Cr[0], cr1 = P ? Cr[3] : Cr[1];                    \
    float cz0 = P ? Cz[2] : Cz[0], cz1 = P ? Cz[3] : Cz[1];                    \
    float cn0 = P ? Cn[2] : Cn[0], cn1 = P ? Cn[3] : Cn[1];                    \
    float pr0 = cr0 + fmaf(xv, wiR[0], bR[0]);                                 \
    float pr1 = cr1 + fmaf(xv, wiR[1], bR[1]);                                 \
    float rr0 = __builtin_amdgcn_rcpf(1.0f + __builtin_amdgcn_exp2f(pr0));     \
    float rr1 = __builtin_amdgcn_rcpf(1.0f + __builtin_amdgcn_exp2f(pr1));     \
    float pz0 = cz0 + fmaf(xv, wiZ[0], bZ[0]);                                 \
    float pz1 = cz1 + fmaf(xv, wiZ[1], bZ[1]);                                 \
    float zz0 = __builtin_amdgcn_rcpf(1.0f + __builtin_amdgcn_exp2f(pz0));     \
    float zz1 = __builtin_amdgcn_rcpf(1.0f + __builtin_amdgcn_exp2f(pz1));     \
    float pn0 = fmaf(rr0, cn0 + bHN[0], fmaf(xv, wiN[0], bN[0]));              \
    float pn1 = fmaf(rr1, cn1 + bHN[1], fmaf(xv, wiN[1], bN[1]));              \
    float u0 = __builtin_amdgcn_rcpf(1.0f + __builtin_amdgcn_exp2f(pn0));      \
    float u1 = __builtin_amdgcn_rcpf(1.0f + __builtin_amdgcn_exp2f(pn1));      \
    float nn0 = fmaf(-2.0f, u0, 1.0f);                                         \
    float nn1 = fmaf(-2.0f, u1, 1.0f);                                         \
    ho[0] = fmaf(zz0, ho[0] - nn0, nn0);                                       \
    ho[1] = fmaf(zz1, ho[1] - nn1, nn1);                                       \
    hbuf[DST][col][T * 8 + grp * 2 + P] = pack2(ho[0], ho[1]);                 \
    __syncthreads();                                                           \
  }

#pragma unroll 1
  for (int t = 0; t < TT; t += 2) {
    GRU_STEP(0, 1, t)
    GRU_STEP(1, 0, t + 1)
  }
#undef GRU_STEP

  {
    int j = T * 16 + grp * 4 + 2 * P;
    size_t base = ((size_t)(b0 + col) * GG + g) * HH + j;
    hout[base] = ho[0];
    hout[base + 1] = ho[1];
  }
}

// One block per b: query -> scores -> softmax -> weighted rep -> out row,
// then broadcast-write the row across all T positions (coalesced float4).
__global__ __launch_bounds__(256) void epilogue(
    const float* __restrict__ ctx, const float* __restrict__ hf,
    const float* __restrict__ Wq, const float* __restrict__ bq,
    const float* __restrict__ Ws, const float* __restrict__ bs,
    const float* __restrict__ Wo, const float* __restrict__ bo,
    const float* __restrict__ logT, float* __restrict__ out, int B) {
  const int b = blockIdx.x;
  const int tid = threadIdx.x;
  __shared__ float sc[DD];
  __shared__ float sw[HH];
  __shared__ float srow[DD];
  if (tid < DD) sc[tid] = ctx[(size_t)b * DD + tid];
  __syncthreads();
  if (tid < HH) {
    float q = bq[tid];
#pragma unroll 4
    for (int d = 0; d < DD; ++d) q = fmaf(sc[d], Wq[d * HH + tid], q);
    float h0 = hf[((size_t)b * 3 + 0) * HH + tid];
    float h1 = hf[((size_t)b * 3 + 1) * HH + tid];
    float h2 = hf[((size_t)b * 3 + 2) * HH + tid];
    float wsv = Ws[tid];
    float s0 = fast_tanh(h0 + q) * wsv;
    float s1 = fast_tanh(h1 + q) * wsv;
    float s2 = fast_tanh(h2 + q) * wsv;
#pragma unroll
    for (int off = 16; off >= 1; off >>= 1) {
      s0 += __shfl_xor(s0, off, 32);
      s1 += __shfl_xor(s1, off, 32);
      s2 += __shfl_xor(s2, off, 32);
    }
    float bsv = bs[0];
    float tmp = fmaxf(__expf(logT[0]), 0.1f);
    float inv = 1.0f / tmp;
    s0 = (s0 + bsv) * inv; s1 = (s1 + bsv) * inv; s2 = (s2 + bsv) * inv;
    float m = fmaxf(s0, fmaxf(s1, s2));
    float e0 = __expf(s0 - m), e1 = __expf(s1 - m), e2 = __expf(s2 - m);
    float den = 1.0f / (e0 + e1 + e2);
    float a0 = e0 * den, a1 = e1 * den, a2 = e2 * den;
    sw[tid] = a0 * h0 + a1 * h1 + a2 * h2;
    if (tid == 0) {
      size_t aoff = (size_t)B * TT * DD + (size_t)b * 3;
      out[aoff] = a0; out[aoff + 1] = a1; out[aoff + 2] = a2;
    }
  }
  __syncthreads();
  if (tid < DD) {
    float o = bo[tid];
#pragma unroll
    for (int h = 0; h < HH; ++h) o = fmaf(sw[h], Wo[h * DD + tid], o);
    srow[tid] = o;
  }
  __syncthreads();
  const float4 v = *(const float4*)&srow[(tid & 31) * 4];
  float4* o4 = (float4*)out + (size_t)b * (TT * DD / 4);
#pragma unroll 4
  for (int i = tid; i < TT * DD / 4; i += 256) {
    o4[i] = v;
  }
}

extern "C" void kernel_launch(void* const* d_in, const int* in_sizes, int n_in,
                              void* d_out, int out_size, void* d_ws, size_t ws_size,
                              hipStream_t stream) {
  const float* x    = (const float*)d_in[0];
  const float* ctx  = (const float*)d_in[1];
  const float* W_ih = (const float*)d_in[2];
  const float* W_hh = (const float*)d_in[3];
  const float* b_ih = (const float*)d_in[4];
  const float* b_hh = (const float*)d_in[5];
  const float* Wq   = (const float*)d_in[6];
  const float* bq   = (const float*)d_in[7];
  const float* Ws   = (const float*)d_in[8];
  const float* bs   = (const float*)d_in[9];
  const float* Wo   = (const float*)d_in[10];
  const float* bo   = (const float*)d_in[11];
  const float* logT = (const float*)d_in[12];
  float* out = (float*)d_out;
  const int B = in_sizes[0] / (TT * GG);

  float* hf = (float*)d_ws;  // B*G*H floats

  dim3 g1((B / 16) * GG);
  gru_scan_mfma4<<<g1, 256, 0, stream>>>(x, W_ih, W_hh, b_ih, b_hh, hf, B);
  epilogue<<<B, 256, 0, stream>>>(ctx, hf, Wq, bq, Ws, bs, Wo, bo, logT, out, B);
}